// Round 10
// baseline (315.101 us; speedup 1.0000x reference)
//
#include <hip/hip_runtime.h>
#include <hip/hip_bf16.h>

#define NB 8192
#define SROW 391

// ---- weight ws layout (floats) ----
#define TW      22848
#define W_WIH   0
#define W_WHH   1536
#define W_BSUM  17920
#define W_WTS   18176
#define W_BTS   22272
#define W_WOS   22336
#define W_BOS   22784
#define W_OUT   68544
#define WO_WIHO 0
#define WO_WHHO 32768
#define WO_BSUM 49152
#define WO_W1   49408
#define WO_B1   53504
#define WO_W2   53568
#define WO_B2   54144
#define WF_TOTAL 122697

// ---- pre-swizzled fragment table (u16 offsets) ----
#define OFF_WHH   0        // [t][q][g][f2][64][8]  49152
#define OFF_WIH   49152    // [t][q][g][64][8]      24576
#define OFF_WTS   73728    // [t][q][f2][64][8]     12288
#define OFF_WIHO  86016    // [q][g][f4][64][8]     32768
#define OFF_WHHO  118784   // [q][g][f2][64][8]     16384
#define OFF_W1    135168   // [q][f2][64][8]         4096
#define FB_TOTAL  139264

typedef unsigned short u16;
typedef __attribute__((ext_vector_type(8))) short short8;
typedef __attribute__((ext_vector_type(8))) _Float16 half8;
typedef __attribute__((ext_vector_type(4))) _Float16 half4;
typedef __attribute__((ext_vector_type(4))) float float4v;

#define MFMAH(a, b, c) __builtin_amdgcn_mfma_f32_16x16x32_f16((a), (b), (c), 0, 0, 0)

__device__ __forceinline__ float bf2f(u16 u){ return __uint_as_float(((unsigned)u) << 16); }
__device__ __forceinline__ u16 f2bf(float f){
  unsigned x = __float_as_uint(f);
  unsigned r = (x + 0x7FFFu + ((x >> 16) & 1u)) >> 16;   // RNE
  return (u16)r;
}
__device__ __forceinline__ u16 f2h(float f){
  _Float16 h = (_Float16)f;     // v_cvt_f16_f32, RNE
  return *(u16*)&h;
}
__device__ __forceinline__ bool isnanf32(float f){
  unsigned x = __float_as_uint(f);
  return (x & 0x7FFFFFFFu) > 0x7F800000u;
}
__device__ __forceinline__ float ldin(const void* p, size_t i, bool isbf){
  if (isbf) return bf2f(((const u16*)p)[i]);
  return ((const float*)p)[i];
}
__device__ __forceinline__ float sigm(float x){ return __fdividef(1.0f, 1.0f + __expf(-x)); }
__device__ __forceinline__ float tanh_f(float x){ return __fdividef(2.0f, 1.0f + __expf(-2.0f * x)) - 1.0f; }

// Fused-denominator LSTM cell update: 5 exp + 2 rcp (was 10 trans).
__device__ __forceinline__ void lstm_cell(float gi, float gf, float gg, float go,
                                          float& cs, float& hs, bool v){
  const float ef = __expf(-gf);
  const float ei = __expf(-gi);
  const float eg = __expf(-2.0f * gg);
  const float eo = __expf(-go);
  const float A = 1.0f + ef, B = 1.0f + ei, C = 1.0f + eg;
  const float BC = B * C;
  const float R = __builtin_amdgcn_rcpf(A * BC);
  const float t = fmaf(-A, eg, A);            // A*(1-eg)
  const float cn = fmaf(cs, BC, t) * R;
  const float ct = fminf(fmaxf(cn, -15.0f), 15.0f);
  const float ec = __expf(-2.0f * ct);
  const float D = 1.0f + eo, E = 1.0f + ec;
  const float S = __builtin_amdgcn_rcpf(D * E);
  const float hn = (1.0f - ec) * S;
  cs = v ? cn : cs;
  hs = v ? hn : hs;
}

__device__ __forceinline__ bool detect_bf(const void* whh0){
  const u16* u = (const u16*)whh0;
  const int l = threadIdx.x & 63;
  int e = (u[2 * l] >> 7) & 0xFF;
  unsigned long long m = __ballot(e >= 100 && e <= 141);
  return __popcll(m) >= 32;
}

struct Seg { int src; int src2; int soff; int dst; int n; };
struct SegTab { Seg s[35]; };
struct PtrTab { const void* p[36]; };

// ---------- kernel W: weights -> fp32; publish dtype flag; zero histogram ----------
__global__ __launch_bounds__(256) void kweights(PtrTab P, SegTab S, float* __restrict__ WF,
                                                const void* __restrict__ whh0, int* __restrict__ flag,
                                                int* __restrict__ ghist){
  const bool isbf = detect_bf(whh0);
  if (blockIdx.x == 0){
    if (threadIdx.x == 0) *flag = isbf ? 1 : 0;
    if (threadIdx.x < 195) ghist[threadIdx.x] = 0;
  }
  Seg sg = S.s[blockIdx.x];
  const void* a = P.p[sg.src];
  const void* b = (sg.src2 >= 0) ? P.p[sg.src2] : nullptr;
  for (int i = threadIdx.x; i < sg.n; i += 256){
    float v = ldin(a, sg.soff + i, isbf);
    if (b) v += ldin(b, sg.soff + i, isbf);
    WF[sg.dst + i] = v;
  }
}

// ---------- kernel G: one-time fragment pre-swizzle -> fp16 fragments ----------
__global__ __launch_bounds__(256) void kfrag(const float* __restrict__ WF, u16* __restrict__ FB){
  const int i = blockIdx.x * 256 + threadIdx.x;   // short8 item id, 17408 total
  short8 v = {0, 0, 0, 0, 0, 0, 0, 0};
  int dst;
  if (i < 6144){                       // WHH: lane|f|g|q|t
    const int lane = i & 63, f = (i >> 6) & 1, g = (i >> 7) & 3, q = (i >> 9) & 3, t = i >> 11;
    const int mrow = g * 64 + q * 16 + (lane & 15);
    const float* src = WF + t * TW + W_WHH + mrow * 64 + f * 32 + (lane >> 4) * 8;
    #pragma unroll
    for (int j = 0; j < 8; ++j) v[j] = (short)f2h(src[j]);
    dst = OFF_WHH + i * 8;
  } else if (i < 9216){                // WIH (aX): lane|g|q|t
    const int k = i - 6144;
    const int lane = k & 63, g = (k >> 6) & 3, q = (k >> 8) & 3, t = k >> 10;
    if ((lane >> 4) == 0){
      const int mrow = g * 64 + q * 16 + (lane & 15);
      const float* src = WF + t * TW + W_WIH + mrow * 6;
      #pragma unroll
      for (int j = 0; j < 6; ++j) v[j] = (short)f2h(src[j]);
    }
    dst = OFF_WIH + k * 8;
  } else if (i < 10752){               // WTS (aT): lane|f|q|t
    const int k = i - 9216;
    const int lane = k & 63, f = (k >> 6) & 1, q = (k >> 7) & 3, t = k >> 9;
    const int row = q * 16 + (lane & 15);
    const float* src = WF + t * TW + W_WTS + row * 64 + f * 32 + (lane >> 4) * 8;
    #pragma unroll
    for (int j = 0; j < 8; ++j) v[j] = (short)f2h(src[j]);
    dst = OFF_WTS + k * 8;
  } else if (i < 14848){               // WIHO (aI): lane|f4|g|q
    const int k = i - 10752;
    const int lane = k & 63, f = (k >> 6) & 3, g = (k >> 8) & 3, q = (k >> 10) & 3;
    const int mrow = g * 64 + q * 16 + (lane & 15);
    const float* src = WF + W_OUT + WO_WIHO + mrow * 128 + f * 32 + (lane >> 4) * 8;
    #pragma unroll
    for (int j = 0; j < 8; ++j) v[j] = (short)f2h(src[j]);
    dst = OFF_WIHO + k * 8;
  } else if (i < 16896){               // WHHO (aH): lane|f2|g|q
    const int k = i - 14848;
    const int lane = k & 63, f = (k >> 6) & 1, g = (k >> 7) & 3, q = (k >> 9) & 3;
    const int mrow = g * 64 + q * 16 + (lane & 15);
    const float* src = WF + W_OUT + WO_WHHO + mrow * 64 + f * 32 + (lane >> 4) * 8;
    #pragma unroll
    for (int j = 0; j < 8; ++j) v[j] = (short)f2h(src[j]);
    dst = OFF_WHHO + k * 8;
  } else {                             // W1 (a1): lane|f2|q
    const int k = i - 16896;
    const int lane = k & 63, f = (k >> 6) & 1, q = (k >> 7) & 3;
    const int row = q * 16 + (lane & 15);
    const float* src = WF + W_OUT + WO_W1 + row * 64 + f * 32 + (lane >> 4) * 8;
    #pragma unroll
    for (int j = 0; j < 8; ++j) v[j] = (short)f2h(src[j]);
    dst = OFF_W1 + k * 8;
  }
  *(short8*)&FB[dst] = v;
}

// ---------- kernel P: wave-per-batch prep + histogram rank; sTx/xpartT fp16 ----------
__global__ __launch_bounds__(256) void kprep(const void* __restrict__ s,
                                             const void* __restrict__ sh,
                                             const int* __restrict__ hist_len,
                                             const float* __restrict__ WF,
                                             u16* __restrict__ sTx,
                                             int* __restrict__ nar,
                                             u16* __restrict__ xpartT,
                                             const int* __restrict__ flag,
                                             int* __restrict__ ghist,
                                             int* __restrict__ krank){
  __shared__ u16 stage[4][400];
  const bool isbf = (*flag != 0);
  const int t = blockIdx.y;
  const int w = threadIdx.x >> 6;
  const int l = threadIdx.x & 63;
  const int b = blockIdx.x * 4 + w;
  const int hl = hist_len[b];

  const void* base; size_t soff;
  if (t == 0){ base = s; soff = (size_t)b * SROW; }
  else {
    if (hl < 2) return;   // zero-input case via zxp in kfinalM (wave-uniform exit)
    base = sh; soff = ((size_t)b * 2 + ((t == 1) ? 1 : 0)) * SROW;
  }

  float val[7];
  #pragma unroll
  for (int k = 0; k < 7; ++k){
    const int e = k * 64 + l;
    float v = 0.0f;
    if (e < SROW) v = isbf ? bf2f(((const u16*)base)[soff + e]) : ((const float*)base)[soff + e];
    val[k] = v;
  }
  float sOS[7];
  #pragma unroll
  for (int i = 0; i < 7; ++i) sOS[i] = __shfl(val[0], i);

  int n = 0;
  #pragma unroll
  for (int k = 0; k < 7; ++k){
    const int e = k * 64 + l;
    const bool firstf = (e >= 7) && (e < SROW) && ((e - 7) % 6 == 0);
    unsigned long long m = __ballot(firstf && !isnanf32(val[k]));
    n += __popcll(m);
  }

  #pragma unroll
  for (int k = 0; k < 7; ++k){
    const int e = k * 64 + l;
    if (e >= 7 && e < SROW) stage[w][e] = f2h(isnanf32(val[k]) ? 0.0f : val[k]);
  }

  {
    const int r = l;
    u16 v0 = stage[w][7 + 6 * r],  v1 = stage[w][8 + 6 * r],  v2 = stage[w][9 + 6 * r];
    u16 v3 = stage[w][10 + 6 * r], v4 = stage[w][11 + 6 * r], v5 = stage[w][12 + 6 * r];
    uint4 wv;
    wv.x = (uint)v0 | ((uint)v1 << 16);
    wv.y = (uint)v2 | ((uint)v3 << 16);
    wv.z = (uint)v4 | ((uint)v5 << 16);
    wv.w = 0u;
    *(uint4*)&sTx[((size_t)(t * NB + b) * 64 + r) * 8] = wv;
  }
  if (l == 0){
    nar[t * NB + b] = n;
    const int key = 64 - min(max(n, 0), 64);   // descending n (LPT)
    krank[t * NB + b] = atomicAdd(&ghist[t * 65 + key], 1);
  }

  const float* wos = WF + t * TW + W_WOS;
  const float* bos = WF + t * TW + W_BOS;
  float acc = bos[l];
  #pragma unroll
  for (int i = 0; i < 7; ++i) acc = fmaf(wos[l * 7 + i], sOS[i], acc);
  xpartT[((size_t)(t * NB + b)) * 128 + l] = f2h(fmaxf(acc, 0.0f));
}

// ---------- scatter with local scan (scan launch folded in) ----------
__global__ __launch_bounds__(256) void kscatW(const int* __restrict__ hist_len,
                                              const int* __restrict__ nar,
                                              const int* __restrict__ ghist,
                                              const int* __restrict__ krank,
                                              int* __restrict__ idx,
                                              int* __restrict__ cnt){
  __shared__ int o[65];
  const int t = blockIdx.y;
  if (threadIdx.x == 0){
    int acc = 0;
    for (int k = 0; k < 65; ++k){ o[k] = acc; acc += ghist[t * 65 + k]; }
    if (blockIdx.x == 0) cnt[t] = acc;
  }
  __syncthreads();
  for (int i = threadIdx.x; i < 512; i += 256){
    const int b = blockIdx.x * 512 + i;
    if (t > 0 && hist_len[b] < 2) continue;
    const int key = 64 - min(max(nar[t * NB + b], 0), 64);
    idx[t * NB + o[key] + krank[t * NB + b]] = b;
  }
}

// ---------- kernel M: 2-wave blocks, 32 rows/wave (ILP x2, barrier scope /2) ----------
__global__ __launch_bounds__(128, 2) void kmainM(const int* __restrict__ nar,
                                                 const float* __restrict__ WF,
                                                 const u16* __restrict__ FB,
                                                 const u16* __restrict__ sTx,
                                                 u16* __restrict__ xpartT,
                                                 const int* __restrict__ idx,
                                                 const int* __restrict__ cnt,
                                                 u16* __restrict__ zxp){
  __shared__ u16 hH[2][16 * 72];
  __shared__ float zh[64];
  __shared__ float zg[256];
  const int t = blockIdx.y;
  const float* Wt = WF + t * TW;

  // ---- block 0: zero-input trajectory + zxp (t=1,2); 128 threads, 2 rows/thread ----
  if (blockIdx.x == 0){
    if (t == 0) return;
    const int u = threadIdx.x & 63;
    const int w = threadIdx.x >> 6;
    const int r0 = (int)threadIdx.x;           // 0..127
    const int r1 = r0 + 128;                   // 128..255
    const float* wr0 = Wt + W_WHH + r0 * 64;
    const float* wr1 = Wt + W_WHH + r1 * 64;
    const float b0 = Wt[W_BSUM + r0];
    const float b1 = Wt[W_BSUM + r1];
    if (w == 0) zh[u] = 0.0f;
    float zc = 0.0f;
    __syncthreads();
    for (int step = 0; step < 64; ++step){
      float a0 = 0.0f, a1 = 0.0f;
      #pragma unroll
      for (int k = 0; k < 64; ++k){
        const float hv = zh[k];
        a0 = fmaf(wr0[k], hv, a0);
        a1 = fmaf(wr1[k], hv, a1);
      }
      zg[r0] = b0 + a0;
      zg[r1] = b1 + a1;
      __syncthreads();
      if (w == 0){
        float gi = zg[u], gf = zg[64 + u], gg = zg[128 + u], go = zg[192 + u];
        zc = sigm(gf) * zc + sigm(gi) * tanh_f(gg);
        zh[u] = sigm(go) * tanh_f(zc);
      }
      __syncthreads();
    }
    if (w == 0){
      float acc = Wt[W_BTS + u];
      const float* wts = Wt + W_WTS + u * 64;
      for (int k = 0; k < 64; ++k) acc = fmaf(wts[k], zh[k], acc);
      zxp[(t - 1) * 128 + 64 + u] = f2h(fmaxf(acc, 0.0f));
      zxp[(t - 1) * 128 + u]      = f2h(fmaxf(Wt[W_BOS + u], 0.0f));
    }
    return;
  }

  const int c = cnt[t];
  const int bx = blockIdx.x - 1;
  if (bx * 16 >= c) return;

  const int lane = threadIdx.x & 63;
  const int w    = __builtin_amdgcn_readfirstlane((int)(threadIdx.x >> 6));   // 0..1
  const int nlo  = lane & 15;
  const int quad = lane >> 4;

  for (int i = threadIdx.x; i < 16 * 72; i += 128){ hH[0][i] = 0; }

  // wave w owns Q-slots {2w, 2w+1}: rows [Q*16, Q*16+16) of each gate
  half8 aW[2][4][2], aX[2][4];
  float4v binit[2][4];
  #pragma unroll
  for (int s = 0; s < 2; ++s){
    const int Q = 2 * w + s;
    #pragma unroll
    for (int g = 0; g < 4; ++g){
      #pragma unroll
      for (int f = 0; f < 2; ++f)
        aW[s][g][f] = *(const half8*)&FB[OFF_WHH + (((((t * 4 + Q) * 4 + g) * 2 + f) * 64 + lane)) * 8];
      aX[s][g] = *(const half8*)&FB[OFF_WIH + ((((t * 4 + Q) * 4 + g) * 64 + lane)) * 8];
      binit[s][g] = *(const float4v*)(Wt + W_BSUM + g * 64 + Q * 16 + quad * 4);
    }
  }

  const int pos = min(bx * 16 + nlo, c - 1);   // clamp replaces pad
  const int bb = idx[t * NB + pos];
  const int n_l = nar[t * NB + bb];
  const u16* sB = sTx + (size_t)(t * NB + bb) * 512;
  int nmax = n_l;
  #pragma unroll
  for (int o = 1; o < 16; o <<= 1) nmax = max(nmax, __shfl_xor(nmax, o));

  float c_st[2][4], h_st[2][4];
  #pragma unroll
  for (int s = 0; s < 2; ++s)
    #pragma unroll
    for (int r = 0; r < 4; ++r){ c_st[s][r] = 0.0f; h_st[s][r] = 0.0f; }

  half8 xcur = (half8)(_Float16)0, xnxt;
  if (lane < 16) xcur = *(const half8*)sB;

  __syncthreads();

  for (int step = 0; step < nmax; ++step){
    xnxt = (half8)(_Float16)0;
    const int ns = min(step + 1, 63);
    if (lane < 16) xnxt = *(const half8*)(sB + (size_t)ns * 8);

    const u16* rH = hH[step & 1];
    u16* wH = hH[(step + 1) & 1];

    const int hb = nlo * 72 + quad * 8;
    half8 h0 = *(const half8*)&rH[hb];
    half8 h1 = *(const half8*)&rH[hb + 32];

    float4v acc[2][4];
    #pragma unroll
    for (int s = 0; s < 2; ++s)
      #pragma unroll
      for (int g = 0; g < 4; ++g){
        float4v a = binit[s][g];
        a = MFMAH(aX[s][g], xcur, a);
        a = MFMAH(aW[s][g][0], h0, a);
        a = MFMAH(aW[s][g][1], h1, a);
        acc[s][g] = a;
      }

    const bool v = (step < n_l);
    #pragma unroll
    for (int s = 0; s < 2; ++s){
      #pragma unroll
      for (int r = 0; r < 4; ++r)
        lstm_cell(acc[s][0][r], acc[s][1][r], acc[s][2][r], acc[s][3][r],
                  c_st[s][r], h_st[s][r], v);
      half4 hv = {(_Float16)h_st[s][0], (_Float16)h_st[s][1],
                  (_Float16)h_st[s][2], (_Float16)h_st[s][3]};
      const int off = nlo * 72 + (2 * w + s) * 16 + quad * 4;
      *(uint2*)&wH[off] = *(uint2*)&hv;
    }

    xcur = xnxt;
    __syncthreads();   // single barrier: dbuf removes WAR hazard
  }

  // xTS epilogue from final h buffer (both Q-slots per wave)
  const u16* fH = hH[nmax & 1];
  const int hb = nlo * 72 + quad * 8;
  const half8 fh0 = *(const half8*)&fH[hb];
  const half8 fh1 = *(const half8*)&fH[hb + 32];
  #pragma unroll
  for (int s = 0; s < 2; ++s){
    const int Q = 2 * w + s;
    half8 aT0 = *(const half8*)&FB[OFF_WTS + ((((t * 4 + Q) * 2 + 0) * 64 + lane)) * 8];
    half8 aT1 = *(const half8*)&FB[OFF_WTS + ((((t * 4 + Q) * 2 + 1) * 64 + lane)) * 8];
    float4v a = *(const float4v*)(Wt + W_BTS + Q * 16 + quad * 4);
    a = MFMAH(aT0, fh0, a);
    a = MFMAH(aT1, fh1, a);
    u16 o4[4];
    #pragma unroll
    for (int r = 0; r < 4; ++r) o4[r] = f2h(fmaxf(a[r], 0.0f));
    size_t oidx = ((size_t)(t * NB + bb)) * 128 + 64 + Q * 16 + quad * 4;
    uint2 wv;
    wv.x = (uint)o4[0] | ((uint)o4[1] << 16);
    wv.y = (uint)o4[2] | ((uint)o4[3] << 16);
    *(uint2*)&xpartT[oidx] = wv;
  }
}

// ---------- kernel F: outer LSTM via fp16 MFMA (3 steps) + MLP; 32-batch tiles ----------
__global__ __launch_bounds__(256) void kfinalM(const float* __restrict__ WF,
                                               const u16* __restrict__ FB,
                                               const u16* __restrict__ xpartT,
                                               const u16* __restrict__ zxp,
                                               const int* __restrict__ hist_len,
                                               void* __restrict__ out,
                                               const int* __restrict__ flag){
  __shared__ u16 hH[32 * 72];
  __shared__ float x1T[32 * 68];
  const bool isbf = (*flag != 0);
  const int b0   = blockIdx.x * 32;
  const int lane = threadIdx.x & 63;
  const int q    = __builtin_amdgcn_readfirstlane((int)(threadIdx.x >> 6));
  const int nlo  = lane & 15;
  const int quad = lane >> 4;

  for (int i = threadIdx.x; i < 32 * 72; i += 256){ hH[i] = 0; }

  const float* WO = WF + W_OUT;
  int hl2[2];
  #pragma unroll
  for (int nt = 0; nt < 2; ++nt) hl2[nt] = hist_len[b0 + nt * 16 + nlo];

  half8 aI[4][4], aH[4][2];
  float4v bi4[4];
  #pragma unroll
  for (int g = 0; g < 4; ++g){
    #pragma unroll
    for (int f = 0; f < 4; ++f)
      aI[g][f] = *(const half8*)&FB[OFF_WIHO + ((((q * 4 + g) * 4 + f) * 64 + lane)) * 8];
    #pragma unroll
    for (int f = 0; f < 2; ++f)
      aH[g][f] = *(const half8*)&FB[OFF_WHHO + ((((q * 4 + g) * 2 + f) * 64 + lane)) * 8];
    bi4[g] = *(const float4v*)(WO + WO_BSUM + g * 64 + q * 16 + quad * 4);
  }

  float c_st[2][4], h_st[2][4];
  #pragma unroll
  for (int nt = 0; nt < 2; ++nt)
    #pragma unroll
    for (int r = 0; r < 4; ++r){ c_st[nt][r] = 0.0f; h_st[nt][r] = 0.0f; }
  __syncthreads();

  for (int p = 0; p < 3; ++p){
    float4v acc[4][2];
    #pragma unroll
    for (int nt = 0; nt < 2; ++nt){
      const int bb = b0 + nt * 16 + nlo;
      const int tt = 2 - ((p - hl2[nt] + 2) % 3);
      const u16* xb = (tt > 0 && hl2[nt] < 2) ? (zxp + (tt - 1) * 128)
                                              : xpartT + ((size_t)(tt * NB + bb)) * 128;
      half8 xf[4];
      #pragma unroll
      for (int f = 0; f < 4; ++f) xf[f] = *(const half8*)(xb + f * 32 + quad * 8);
      const int hb = (nt * 16 + nlo) * 72 + quad * 8;
      half8 h0 = *(const half8*)&hH[hb];
      half8 h1 = *(const half8*)&hH[hb + 32];
      #pragma unroll
      for (int g = 0; g < 4; ++g){
        float4v a = bi4[g];
        #pragma unroll
        for (int f = 0; f < 4; ++f) a = MFMAH(aI[g][f], xf[f], a);
        a = MFMAH(aH[g][0], h0, a);
        a = MFMAH(aH[g][1], h1, a);
        acc[g][nt] = a;
      }
    }
    __syncthreads();
    #pragma unroll
    for (int nt = 0; nt < 2; ++nt){
      const bool v = (p <= hl2[nt]);
      #pragma unroll
      for (int r = 0; r < 4; ++r)
        lstm_cell(acc[0][nt][r], acc[1][nt][r], acc[2][nt][r], acc[3][nt][r],
                  c_st[nt][r], h_st[nt][r], v);
      half4 hv = {(_Float16)h_st[nt][0], (_Float16)h_st[nt][1],
                  (_Float16)h_st[nt][2], (_Float16)h_st[nt][3]};
      const int off = (nt * 16 + nlo) * 72 + q * 16 + quad * 4;
      *(uint2*)&hH[off] = *(uint2*)&hv;
    }
    __syncthreads();
  }

  half8 a1[2];
  #pragma unroll
  for (int f = 0; f < 2; ++f)
    a1[f] = *(const half8*)&FB[OFF_W1 + (((q * 2 + f) * 64 + lane)) * 8];
  float4v b1v = *(const float4v*)(WO + WO_B1 + q * 16 + quad * 4);
  #pragma unroll
  for (int nt = 0; nt < 2; ++nt){
    const int hb = (nt * 16 + nlo) * 72 + quad * 8;
    float4v a = b1v;
    a = MFMAH(a1[0], *(const half8*)&hH[hb], a);
    a = MFMAH(a1[1], *(const half8*)&hH[hb + 32], a);
    float4v rv;
    #pragma unroll
    for (int r = 0; r < 4; ++r) rv[r] = fmaxf(a[r], 0.0f);
    *(float4v*)&x1T[(nt * 16 + nlo) * 68 + q * 16 + quad * 4] = rv;
  }
  __syncthreads();

  const int bloc = threadIdx.x >> 3;       // 0..31
  const int r0 = threadIdx.x & 7;
  const float* w2 = WO + WO_W2;
  const float* b2 = WO + WO_B2;
  for (int r = r0; r < 9; r += 8){
    float acc = b2[r];
    const float* wr = w2 + r * 64;
    #pragma unroll
    for (int k = 0; k < 64; ++k) acc = fmaf(wr[k], x1T[bloc * 68 + k], acc);
    if (isbf) ((u16*)out)[(size_t)(b0 + bloc) * 9 + r] = f2bf(acc);
    else      ((float*)out)[(size_t)(b0 + bloc) * 9 + r] = acc;
  }
}

extern "C" void kernel_launch(void* const* d_in, const int* in_sizes, int n_in,
                              void* d_out, int out_size, void* d_ws, size_t ws_size,
                              hipStream_t stream){
  char* ws = (char*)d_ws;
  float* WF = (float*)ws;
  size_t off = ((size_t)WF_TOTAL * 4 + 255) & ~(size_t)255;
  u16* sTx = (u16*)(ws + off);    off += (size_t)3 * NB * 512 * 2;
  u16* xpartT = (u16*)(ws + off); off += (size_t)3 * NB * 128 * 2;
  int* nar = (int*)(ws + off);    off += (size_t)3 * NB * 4;
  int* flag = (int*)(ws + off);   off += 256;
  int* cnt  = (int*)(ws + off);   off += 256;
  int* ghist = (int*)(ws + off);  off += 3 * 65 * 4 + 64;
  int* idx  = (int*)(ws + off);   off += (size_t)3 * NB * 4;
  int* krank = (int*)(ws + off);  off += (size_t)3 * NB * 4;
  u16* zxp  = (u16*)(ws + off);   off += 2 * 128 * 2;
  u16* FB   = (u16*)(ws + off);   off += (size_t)FB_TOTAL * 2;

  PtrTab P;
  for (int i = 0; i < 36; ++i) P.p[i] = d_in[i];

  SegTab S;
  int si = 0;
  for (int t = 0; t < 3; ++t){
    int base = 4 + 8 * t;
    int d = t * TW;
    S.s[si++] = { base + 2, -1,       0,     d + W_WIH,         1536 };
    S.s[si++] = { base + 3, -1,       0,     d + W_WHH,         8192 };
    S.s[si++] = { base + 3, -1,       8192,  d + W_WHH + 8192,  8192 };
    S.s[si++] = { base + 4, base + 5, 0,     d + W_BSUM,        256  };
    S.s[si++] = { base + 6, -1,       0,     d + W_WTS,         4096 };
    S.s[si++] = { base + 7, -1,       0,     d + W_BTS,         64   };
    S.s[si++] = { base + 0, -1,       0,     d + W_WOS,         448  };
    S.s[si++] = { base + 1, -1,       0,     d + W_BOS,         64   };
  }
  {
    int O = W_OUT;
    for (int k = 0; k < 4; ++k)
      S.s[si++] = { 28, -1, k * 8192, O + WO_WIHO + k * 8192, 8192 };
    S.s[si++] = { 29, -1, 0,    O + WO_WHHO,        8192 };
    S.s[si++] = { 29, -1, 8192, O + WO_WHHO + 8192, 8192 };
    S.s[si++] = { 30, 31, 0,    O + WO_BSUM,        256  };
    S.s[si++] = { 32, -1, 0,    O + WO_W1,          4096 };
    S.s[si++] = { 33, -1, 0,    O + WO_B1,          64   };
    S.s[si++] = { 34, -1, 0,    O + WO_W2,          576  };
    S.s[si++] = { 35, -1, 0,    O + WO_B2,          9    };
  }

  const int* hl_ptr = (const int*)d_in[3];

  kweights<<<dim3(35), 256, 0, stream>>>(P, S, WF, d_in[7], flag, ghist);
  kfrag<<<dim3(68), 256, 0, stream>>>(WF, FB);
  kprep<<<dim3(NB / 4, 3), 256, 0, stream>>>(d_in[0], d_in[1], hl_ptr, WF, sTx, nar, xpartT, flag, ghist, krank);
  kscatW<<<dim3(16, 3), 256, 0, stream>>>(hl_ptr, nar, ghist, krank, idx, cnt);
  kmainM<<<dim3(513, 3), 128, 0, stream>>>(nar, WF, FB, sTx, xpartT, idx, cnt, zxp);
  kfinalM<<<dim3(NB / 32), 256, 0, stream>>>(WF, FB, xpartT, zxp, hl_ptr, d_out, flag);
}

// Round 11
// 294.198 us; speedup vs baseline: 1.0710x; 1.0710x over previous
//
#include <hip/hip_runtime.h>
#include <hip/hip_bf16.h>

#define NB 8192
#define SROW 391

// ---- weight ws layout (floats) ----
#define TW      22848
#define W_WIH   0
#define W_WHH   1536
#define W_BSUM  17920
#define W_WTS   18176
#define W_BTS   22272
#define W_WOS   22336
#define W_BOS   22784
#define W_OUT   68544
#define WO_WIHO 0
#define WO_WHHO 32768
#define WO_BSUM 49152
#define WO_W1   49408
#define WO_B1   53504
#define WO_W2   53568
#define WO_B2   54144
#define WF_TOTAL 122697

// ---- pre-swizzled fragment table (u16 offsets) ----
#define OFF_WHH   0        // [t][q][g][f2][64][8]  49152
#define OFF_WIH   49152    // [t][q][g][64][8]      24576
#define OFF_WTS   73728    // [t][q][f2][64][8]     12288
#define OFF_WIHO  86016    // [q][g][f4][64][8]     32768
#define OFF_WHHO  118784   // [q][g][f2][64][8]     16384
#define OFF_W1    135168   // [q][f2][64][8]         4096
#define FB_TOTAL  139264

typedef unsigned short u16;
typedef __attribute__((ext_vector_type(8))) short short8;
typedef __attribute__((ext_vector_type(8))) _Float16 half8;
typedef __attribute__((ext_vector_type(4))) _Float16 half4;
typedef __attribute__((ext_vector_type(4))) float float4v;

#define MFMAH(a, b, c) __builtin_amdgcn_mfma_f32_16x16x32_f16((a), (b), (c), 0, 0, 0)

__device__ __forceinline__ float bf2f(u16 u){ return __uint_as_float(((unsigned)u) << 16); }
__device__ __forceinline__ u16 f2bf(float f){
  unsigned x = __float_as_uint(f);
  unsigned r = (x + 0x7FFFu + ((x >> 16) & 1u)) >> 16;   // RNE
  return (u16)r;
}
__device__ __forceinline__ u16 f2h(float f){
  _Float16 h = (_Float16)f;     // v_cvt_f16_f32, RNE
  return *(u16*)&h;
}
__device__ __forceinline__ bool isnanf32(float f){
  unsigned x = __float_as_uint(f);
  return (x & 0x7FFFFFFFu) > 0x7F800000u;
}
__device__ __forceinline__ float ldin(const void* p, size_t i, bool isbf){
  if (isbf) return bf2f(((const u16*)p)[i]);
  return ((const float*)p)[i];
}
__device__ __forceinline__ float sigm(float x){ return __fdividef(1.0f, 1.0f + __expf(-x)); }
__device__ __forceinline__ float tanh_f(float x){ return __fdividef(2.0f, 1.0f + __expf(-2.0f * x)) - 1.0f; }

// Fused-denominator LSTM cell update: 5 exp + 2 rcp (was 10 trans).
__device__ __forceinline__ void lstm_cell(float gi, float gf, float gg, float go,
                                          float& cs, float& hs, bool v){
  const float ef = __expf(-gf);
  const float ei = __expf(-gi);
  const float eg = __expf(-2.0f * gg);
  const float eo = __expf(-go);
  const float A = 1.0f + ef, B = 1.0f + ei, C = 1.0f + eg;
  const float BC = B * C;
  const float R = __builtin_amdgcn_rcpf(A * BC);
  const float t = fmaf(-A, eg, A);            // A*(1-eg)
  const float cn = fmaf(cs, BC, t) * R;
  const float ct = fminf(fmaxf(cn, -15.0f), 15.0f);
  const float ec = __expf(-2.0f * ct);
  const float D = 1.0f + eo, E = 1.0f + ec;
  const float S = __builtin_amdgcn_rcpf(D * E);
  const float hn = (1.0f - ec) * S;
  cs = v ? cn : cs;
  hs = v ? hn : hs;
}

__device__ __forceinline__ bool detect_bf(const void* whh0){
  const u16* u = (const u16*)whh0;
  const int l = threadIdx.x & 63;
  int e = (u[2 * l] >> 7) & 0xFF;
  unsigned long long m = __ballot(e >= 100 && e <= 141);
  return __popcll(m) >= 32;
}

struct Seg { int src; int src2; int soff; int dst; int n; };
struct SegTab { Seg s[35]; };
struct PtrTab { const void* p[36]; };

// ---------- kernel W: weights -> fp32; publish dtype flag; zero histogram ----------
__global__ __launch_bounds__(256) void kweights(PtrTab P, SegTab S, float* __restrict__ WF,
                                                const void* __restrict__ whh0, int* __restrict__ flag,
                                                int* __restrict__ ghist){
  const bool isbf = detect_bf(whh0);
  if (blockIdx.x == 0){
    if (threadIdx.x == 0) *flag = isbf ? 1 : 0;
    if (threadIdx.x < 195) ghist[threadIdx.x] = 0;
  }
  Seg sg = S.s[blockIdx.x];
  const void* a = P.p[sg.src];
  const void* b = (sg.src2 >= 0) ? P.p[sg.src2] : nullptr;
  for (int i = threadIdx.x; i < sg.n; i += 256){
    float v = ldin(a, sg.soff + i, isbf);
    if (b) v += ldin(b, sg.soff + i, isbf);
    WF[sg.dst + i] = v;
  }
}

// ---------- kernel G: one-time fragment pre-swizzle -> fp16 fragments ----------
__global__ __launch_bounds__(256) void kfrag(const float* __restrict__ WF, u16* __restrict__ FB){
  const int i = blockIdx.x * 256 + threadIdx.x;   // short8 item id, 17408 total
  short8 v = {0, 0, 0, 0, 0, 0, 0, 0};
  int dst;
  if (i < 6144){                       // WHH: lane|f|g|q|t
    const int lane = i & 63, f = (i >> 6) & 1, g = (i >> 7) & 3, q = (i >> 9) & 3, t = i >> 11;
    const int mrow = g * 64 + q * 16 + (lane & 15);
    const float* src = WF + t * TW + W_WHH + mrow * 64 + f * 32 + (lane >> 4) * 8;
    #pragma unroll
    for (int j = 0; j < 8; ++j) v[j] = (short)f2h(src[j]);
    dst = OFF_WHH + i * 8;
  } else if (i < 9216){                // WIH (aX): lane|g|q|t
    const int k = i - 6144;
    const int lane = k & 63, g = (k >> 6) & 3, q = (k >> 8) & 3, t = k >> 10;
    if ((lane >> 4) == 0){
      const int mrow = g * 64 + q * 16 + (lane & 15);
      const float* src = WF + t * TW + W_WIH + mrow * 6;
      #pragma unroll
      for (int j = 0; j < 6; ++j) v[j] = (short)f2h(src[j]);
    }
    dst = OFF_WIH + k * 8;
  } else if (i < 10752){               // WTS (aT): lane|f|q|t
    const int k = i - 9216;
    const int lane = k & 63, f = (k >> 6) & 1, q = (k >> 7) & 3, t = k >> 9;
    const int row = q * 16 + (lane & 15);
    const float* src = WF + t * TW + W_WTS + row * 64 + f * 32 + (lane >> 4) * 8;
    #pragma unroll
    for (int j = 0; j < 8; ++j) v[j] = (short)f2h(src[j]);
    dst = OFF_WTS + k * 8;
  } else if (i < 14848){               // WIHO (aI): lane|f4|g|q
    const int k = i - 10752;
    const int lane = k & 63, f = (k >> 6) & 3, g = (k >> 8) & 3, q = (k >> 10) & 3;
    const int mrow = g * 64 + q * 16 + (lane & 15);
    const float* src = WF + W_OUT + WO_WIHO + mrow * 128 + f * 32 + (lane >> 4) * 8;
    #pragma unroll
    for (int j = 0; j < 8; ++j) v[j] = (short)f2h(src[j]);
    dst = OFF_WIHO + k * 8;
  } else if (i < 16896){               // WHHO (aH): lane|f2|g|q
    const int k = i - 14848;
    const int lane = k & 63, f = (k >> 6) & 1, g = (k >> 7) & 3, q = (k >> 9) & 3;
    const int mrow = g * 64 + q * 16 + (lane & 15);
    const float* src = WF + W_OUT + WO_WHHO + mrow * 64 + f * 32 + (lane >> 4) * 8;
    #pragma unroll
    for (int j = 0; j < 8; ++j) v[j] = (short)f2h(src[j]);
    dst = OFF_WHHO + k * 8;
  } else {                             // W1 (a1): lane|f2|q
    const int k = i - 16896;
    const int lane = k & 63, f = (k >> 6) & 1, q = (k >> 7) & 3;
    const int row = q * 16 + (lane & 15);
    const float* src = WF + W_OUT + WO_W1 + row * 64 + f * 32 + (lane >> 4) * 8;
    #pragma unroll
    for (int j = 0; j < 8; ++j) v[j] = (short)f2h(src[j]);
    dst = OFF_W1 + k * 8;
  }
  *(short8*)&FB[dst] = v;
}

// ---------- kernel P: wave-per-batch prep + histogram rank; sTx/xpartT fp16 ----------
__global__ __launch_bounds__(256) void kprep(const void* __restrict__ s,
                                             const void* __restrict__ sh,
                                             const int* __restrict__ hist_len,
                                             const float* __restrict__ WF,
                                             u16* __restrict__ sTx,
                                             int* __restrict__ nar,
                                             u16* __restrict__ xpartT,
                                             const int* __restrict__ flag,
                                             int* __restrict__ ghist,
                                             int* __restrict__ krank){
  __shared__ u16 stage[4][400];
  const bool isbf = (*flag != 0);
  const int t = blockIdx.y;
  const int w = threadIdx.x >> 6;
  const int l = threadIdx.x & 63;
  const int b = blockIdx.x * 4 + w;
  const int hl = hist_len[b];

  const void* base; size_t soff;
  if (t == 0){ base = s; soff = (size_t)b * SROW; }
  else {
    if (hl < 2) return;   // zero-input case via zxp in kfinalM (wave-uniform exit)
    base = sh; soff = ((size_t)b * 2 + ((t == 1) ? 1 : 0)) * SROW;
  }

  float val[7];
  #pragma unroll
  for (int k = 0; k < 7; ++k){
    const int e = k * 64 + l;
    float v = 0.0f;
    if (e < SROW) v = isbf ? bf2f(((const u16*)base)[soff + e]) : ((const float*)base)[soff + e];
    val[k] = v;
  }
  float sOS[7];
  #pragma unroll
  for (int i = 0; i < 7; ++i) sOS[i] = __shfl(val[0], i);

  int n = 0;
  #pragma unroll
  for (int k = 0; k < 7; ++k){
    const int e = k * 64 + l;
    const bool firstf = (e >= 7) && (e < SROW) && ((e - 7) % 6 == 0);
    unsigned long long m = __ballot(firstf && !isnanf32(val[k]));
    n += __popcll(m);
  }

  #pragma unroll
  for (int k = 0; k < 7; ++k){
    const int e = k * 64 + l;
    if (e >= 7 && e < SROW) stage[w][e] = f2h(isnanf32(val[k]) ? 0.0f : val[k]);
  }

  {
    const int r = l;
    u16 v0 = stage[w][7 + 6 * r],  v1 = stage[w][8 + 6 * r],  v2 = stage[w][9 + 6 * r];
    u16 v3 = stage[w][10 + 6 * r], v4 = stage[w][11 + 6 * r], v5 = stage[w][12 + 6 * r];
    uint4 wv;
    wv.x = (uint)v0 | ((uint)v1 << 16);
    wv.y = (uint)v2 | ((uint)v3 << 16);
    wv.z = (uint)v4 | ((uint)v5 << 16);
    wv.w = 0u;
    *(uint4*)&sTx[((size_t)(t * NB + b) * 64 + r) * 8] = wv;
  }
  if (l == 0){
    nar[t * NB + b] = n;
    const int key = 64 - min(max(n, 0), 64);   // descending n (LPT)
    krank[t * NB + b] = atomicAdd(&ghist[t * 65 + key], 1);
  }

  const float* wos = WF + t * TW + W_WOS;
  const float* bos = WF + t * TW + W_BOS;
  float acc = bos[l];
  #pragma unroll
  for (int i = 0; i < 7; ++i) acc = fmaf(wos[l * 7 + i], sOS[i], acc);
  xpartT[((size_t)(t * NB + b)) * 128 + l] = f2h(fmaxf(acc, 0.0f));
}

// ---------- scatter with local scan (scan launch folded in) ----------
__global__ __launch_bounds__(256) void kscatW(const int* __restrict__ hist_len,
                                              const int* __restrict__ nar,
                                              const int* __restrict__ ghist,
                                              const int* __restrict__ krank,
                                              int* __restrict__ idx,
                                              int* __restrict__ cnt){
  __shared__ int o[65];
  const int t = blockIdx.y;
  if (threadIdx.x == 0){
    int acc = 0;
    for (int k = 0; k < 65; ++k){ o[k] = acc; acc += ghist[t * 65 + k]; }
    if (blockIdx.x == 0) cnt[t] = acc;
  }
  __syncthreads();
  for (int i = threadIdx.x; i < 512; i += 256){
    const int b = blockIdx.x * 512 + i;
    if (t > 0 && hist_len[b] < 2) continue;
    const int key = 64 - min(max(nar[t * NB + b], 0), 64);
    idx[t * NB + o[key] + krank[t * NB + b]] = b;
  }
}

// ---------- kernel M: R9 structure (4 waves, 16 rows/wave) + setprio on MFMA cluster ----------
__global__ __launch_bounds__(256) void kmainM(const int* __restrict__ nar,
                                              const float* __restrict__ WF,
                                              const u16* __restrict__ FB,
                                              const u16* __restrict__ sTx,
                                              u16* __restrict__ xpartT,
                                              const int* __restrict__ idx,
                                              const int* __restrict__ cnt,
                                              u16* __restrict__ zxp){
  __shared__ u16 hH[2][16 * 72];
  __shared__ float zh[64];
  __shared__ float zg[256];
  const int t = blockIdx.y;
  const float* Wt = WF + t * TW;

  // ---- block 0: zero-input trajectory + zxp (t=1,2) ----
  if (blockIdx.x == 0){
    if (t == 0) return;
    const int u = threadIdx.x & 63;
    const int w = threadIdx.x >> 6;
    const int row = w * 64 + u;
    const float* wr = Wt + W_WHH + row * 64;
    const float bsu = Wt[W_BSUM + row];
    if (w == 0) zh[u] = 0.0f;
    float zc = 0.0f;
    __syncthreads();
    for (int step = 0; step < 64; ++step){
      float a0 = 0.0f, a1 = 0.0f, a2 = 0.0f, a3 = 0.0f;
      #pragma unroll
      for (int k = 0; k < 64; k += 4){
        a0 = fmaf(wr[k],     zh[k],     a0);
        a1 = fmaf(wr[k + 1], zh[k + 1], a1);
        a2 = fmaf(wr[k + 2], zh[k + 2], a2);
        a3 = fmaf(wr[k + 3], zh[k + 3], a3);
      }
      zg[row] = bsu + (a0 + a1) + (a2 + a3);
      __syncthreads();
      if (w == 0){
        float gi = zg[u], gf = zg[64 + u], gg = zg[128 + u], go = zg[192 + u];
        zc = sigm(gf) * zc + sigm(gi) * tanh_f(gg);
        zh[u] = sigm(go) * tanh_f(zc);
      }
      __syncthreads();
    }
    if (w == 0){
      float acc = Wt[W_BTS + u];
      const float* wts = Wt + W_WTS + u * 64;
      for (int k = 0; k < 64; ++k) acc = fmaf(wts[k], zh[k], acc);
      zxp[(t - 1) * 128 + 64 + u] = f2h(fmaxf(acc, 0.0f));
      zxp[(t - 1) * 128 + u]      = f2h(fmaxf(Wt[W_BOS + u], 0.0f));
    }
    return;
  }

  const int c = cnt[t];
  const int bx = blockIdx.x - 1;
  if (bx * 16 >= c) return;

  const int lane = threadIdx.x & 63;
  const int q    = __builtin_amdgcn_readfirstlane((int)(threadIdx.x >> 6));
  const int nlo  = lane & 15;
  const int quad = lane >> 4;

  for (int i = threadIdx.x; i < 16 * 72; i += 256){ hH[0][i] = 0; }

  half8 aW[4][2], aX[4];
  float4v binit[4];
  #pragma unroll
  for (int g = 0; g < 4; ++g){
    #pragma unroll
    for (int f = 0; f < 2; ++f)
      aW[g][f] = *(const half8*)&FB[OFF_WHH + (((((t * 4 + q) * 4 + g) * 2 + f) * 64 + lane)) * 8];
    aX[g] = *(const half8*)&FB[OFF_WIH + ((((t * 4 + q) * 4 + g) * 64 + lane)) * 8];
    binit[g] = *(const float4v*)(Wt + W_BSUM + g * 64 + q * 16 + quad * 4);
  }

  const int pos = min(bx * 16 + nlo, c - 1);   // clamp replaces pad
  const int bb = idx[t * NB + pos];
  const int n_l = nar[t * NB + bb];
  const u16* sB = sTx + (size_t)(t * NB + bb) * 512;
  int nmax = n_l;
  #pragma unroll
  for (int o = 1; o < 16; o <<= 1) nmax = max(nmax, __shfl_xor(nmax, o));

  float c_st[4], h_st[4];
  #pragma unroll
  for (int r = 0; r < 4; ++r){ c_st[r] = 0.0f; h_st[r] = 0.0f; }

  half8 xcur = (half8)(_Float16)0, xnxt;
  if (lane < 16) xcur = *(const half8*)sB;

  __syncthreads();

  for (int step = 0; step < nmax; ++step){
    xnxt = (half8)(_Float16)0;
    const int ns = min(step + 1, 63);
    if (lane < 16) xnxt = *(const half8*)(sB + (size_t)ns * 8);

    const u16* rH = hH[step & 1];
    u16* wH = hH[(step + 1) & 1];

    const int hb = nlo * 72 + quad * 8;
    half8 h0 = *(const half8*)&rH[hb];
    half8 h1 = *(const half8*)&rH[hb + 32];

    __builtin_amdgcn_s_setprio(1);
    float4v acc[4];
    #pragma unroll
    for (int g = 0; g < 4; ++g){
      float4v a = binit[g];
      a = MFMAH(aX[g], xcur, a);
      a = MFMAH(aW[g][0], h0, a);
      a = MFMAH(aW[g][1], h1, a);
      acc[g] = a;
    }
    __builtin_amdgcn_s_setprio(0);

    const bool v = (step < n_l);
    #pragma unroll
    for (int r = 0; r < 4; ++r)
      lstm_cell(acc[0][r], acc[1][r], acc[2][r], acc[3][r], c_st[r], h_st[r], v);

    half4 hv = {(_Float16)h_st[0], (_Float16)h_st[1], (_Float16)h_st[2], (_Float16)h_st[3]};
    const int off = nlo * 72 + q * 16 + quad * 4;
    *(uint2*)&wH[off] = *(uint2*)&hv;

    xcur = xnxt;
    __syncthreads();   // single barrier: dbuf removes WAR hazard
  }

  // xTS epilogue from final h buffer
  const u16* fH = hH[nmax & 1];
  half8 aT[2];
  #pragma unroll
  for (int f = 0; f < 2; ++f)
    aT[f] = *(const half8*)&FB[OFF_WTS + ((((t * 4 + q) * 2 + f) * 64 + lane)) * 8];
  float4v btsv = *(const float4v*)(Wt + W_BTS + q * 16 + quad * 4);
  {
    const int hb = nlo * 72 + quad * 8;
    float4v a = btsv;
    a = MFMAH(aT[0], *(const half8*)&fH[hb], a);
    a = MFMAH(aT[1], *(const half8*)&fH[hb + 32], a);
    u16 o4[4];
    #pragma unroll
    for (int r = 0; r < 4; ++r) o4[r] = f2h(fmaxf(a[r], 0.0f));
    size_t oidx = ((size_t)(t * NB + bb)) * 128 + 64 + q * 16 + quad * 4;
    uint2 wv;
    wv.x = (uint)o4[0] | ((uint)o4[1] << 16);
    wv.y = (uint)o4[2] | ((uint)o4[3] << 16);
    *(uint2*)&xpartT[oidx] = wv;
  }
}

// ---------- kernel F: outer LSTM via fp16 MFMA (3 steps) + MLP; 16-batch tiles (2 blocks/CU) ----------
__global__ __launch_bounds__(256) void kfinalM(const float* __restrict__ WF,
                                               const u16* __restrict__ FB,
                                               const u16* __restrict__ xpartT,
                                               const u16* __restrict__ zxp,
                                               const int* __restrict__ hist_len,
                                               void* __restrict__ out,
                                               const int* __restrict__ flag){
  __shared__ u16 hH[16 * 72];
  __shared__ float x1T[16 * 68];
  const bool isbf = (*flag != 0);
  const int b0   = blockIdx.x * 16;
  const int lane = threadIdx.x & 63;
  const int q    = __builtin_amdgcn_readfirstlane((int)(threadIdx.x >> 6));
  const int nlo  = lane & 15;
  const int quad = lane >> 4;

  for (int i = threadIdx.x; i < 16 * 72; i += 256){ hH[i] = 0; }

  const float* WO = WF + W_OUT;
  const int hl = hist_len[b0 + nlo];

  half8 aI[4][4], aH[4][2];
  float4v bi4[4];
  #pragma unroll
  for (int g = 0; g < 4; ++g){
    #pragma unroll
    for (int f = 0; f < 4; ++f)
      aI[g][f] = *(const half8*)&FB[OFF_WIHO + ((((q * 4 + g) * 4 + f) * 64 + lane)) * 8];
    #pragma unroll
    for (int f = 0; f < 2; ++f)
      aH[g][f] = *(const half8*)&FB[OFF_WHHO + ((((q * 4 + g) * 2 + f) * 64 + lane)) * 8];
    bi4[g] = *(const float4v*)(WO + WO_BSUM + g * 64 + q * 16 + quad * 4);
  }

  float c_st[4], h_st[4];
  #pragma unroll
  for (int r = 0; r < 4; ++r){ c_st[r] = 0.0f; h_st[r] = 0.0f; }
  __syncthreads();

  for (int p = 0; p < 3; ++p){
    const int bb = b0 + nlo;
    const int tt = 2 - ((p - hl + 2) % 3);
    const u16* xb = (tt > 0 && hl < 2) ? (zxp + (tt - 1) * 128)
                                       : xpartT + ((size_t)(tt * NB + bb)) * 128;
    half8 xf[4];
    #pragma unroll
    for (int f = 0; f < 4; ++f) xf[f] = *(const half8*)(xb + f * 32 + quad * 8);
    const int hb = nlo * 72 + quad * 8;
    half8 h0 = *(const half8*)&hH[hb];
    half8 h1 = *(const half8*)&hH[hb + 32];
    float4v acc[4];
    #pragma unroll
    for (int g = 0; g < 4; ++g){
      float4v a = bi4[g];
      #pragma unroll
      for (int f = 0; f < 4; ++f) a = MFMAH(aI[g][f], xf[f], a);
      a = MFMAH(aH[g][0], h0, a);
      a = MFMAH(aH[g][1], h1, a);
      acc[g] = a;
    }
    __syncthreads();
    {
      const bool v = (p <= hl);
      #pragma unroll
      for (int r = 0; r < 4; ++r)
        lstm_cell(acc[0][r], acc[1][r], acc[2][r], acc[3][r], c_st[r], h_st[r], v);
      half4 hv = {(_Float16)h_st[0], (_Float16)h_st[1],
                  (_Float16)h_st[2], (_Float16)h_st[3]};
      const int off = nlo * 72 + q * 16 + quad * 4;
      *(uint2*)&hH[off] = *(uint2*)&hv;
    }
    __syncthreads();
  }

  half8 a1[2];
  #pragma unroll
  for (int f = 0; f < 2; ++f)
    a1[f] = *(const half8*)&FB[OFF_W1 + (((q * 2 + f) * 64 + lane)) * 8];
  float4v b1v = *(const float4v*)(WO + WO_B1 + q * 16 + quad * 4);
  {
    const int hb = nlo * 72 + quad * 8;
    float4v a = b1v;
    a = MFMAH(a1[0], *(const half8*)&hH[hb], a);
    a = MFMAH(a1[1], *(const half8*)&hH[hb + 32], a);
    float4v rv;
    #pragma unroll
    for (int r = 0; r < 4; ++r) rv[r] = fmaxf(a[r], 0.0f);
    *(float4v*)&x1T[nlo * 68 + q * 16 + quad * 4] = rv;
  }
  __syncthreads();

  const int bloc = threadIdx.x >> 4;       // 0..15
  const int r0 = threadIdx.x & 15;
  const float* w2 = WO + WO_W2;
  const float* b2 = WO + WO_B2;
  if (r0 < 9){
    float acc = b2[r0];
    const float* wr = w2 + r0 * 64;
    #pragma unroll
    for (int k = 0; k < 64; ++k) acc = fmaf(wr[k], x1T[bloc * 68 + k], acc);
    if (isbf) ((u16*)out)[(size_t)(b0 + bloc) * 9 + r0] = f2bf(acc);
    else      ((float*)out)[(size_t)(b0 + bloc) * 9 + r0] = acc;
  }
}

extern "C" void kernel_launch(void* const* d_in, const int* in_sizes, int n_in,
                              void* d_out, int out_size, void* d_ws, size_t ws_size,
                              hipStream_t stream){
  char* ws = (char*)d_ws;
  float* WF = (float*)ws;
  size_t off = ((size_t)WF_TOTAL * 4 + 255) & ~(size_t)255;
  u16* sTx = (u16*)(ws + off);    off += (size_t)3 * NB * 512 * 2;
  u16* xpartT = (u16*)(ws + off); off += (size_t)3 * NB * 128 * 2;
  int* nar = (int*)(ws + off);    off += (size_t)3 * NB * 4;
  int* flag = (int*)(ws + off);   off += 256;
  int* cnt  = (int*)(ws + off);   off += 256;
  int* ghist = (int*)(ws + off);  off += 3 * 65 * 4 + 64;
  int* idx  = (int*)(ws + off);   off += (size_t)3 * NB * 4;
  int* krank = (int*)(ws + off);  off += (size_t)3 * NB * 4;
  u16* zxp  = (u16*)(ws + off);   off += 2 * 128 * 2;
  u16* FB   = (u16*)(ws + off);   off += (size_t)FB_TOTAL * 2;

  PtrTab P;
  for (int i = 0; i < 36; ++i) P.p[i] = d_in[i];

  SegTab S;
  int si = 0;
  for (int t = 0; t < 3; ++t){
    int base = 4 + 8 * t;
    int d = t * TW;
    S.s[si++] = { base + 2, -1,       0,     d + W_WIH,         1536 };
    S.s[si++] = { base + 3, -1,       0,     d + W_WHH,         8192 };
    S.s[si++] = { base + 3, -1,       8192,  d + W_WHH + 8192,  8192 };
    S.s[si++] = { base + 4, base + 5, 0,     d + W_BSUM,        256  };
    S.s[si++] = { base + 6, -1,       0,     d + W_WTS,         4096 };
    S.s[si++] = { base + 7, -1,       0,     d + W_BTS,         64   };
    S.s[si++] = { base + 0, -1,       0,     d + W_WOS,         448  };
    S.s[si++] = { base + 1, -1,       0,     d + W_BOS,         64   };
  }
  {
    int O = W_OUT;
    for (int k = 0; k < 4; ++k)
      S.s[si++] = { 28, -1, k * 8192, O + WO_WIHO + k * 8192, 8192 };
    S.s[si++] = { 29, -1, 0,    O + WO_WHHO,        8192 };
    S.s[si++] = { 29, -1, 8192, O + WO_WHHO + 8192, 8192 };
    S.s[si++] = { 30, 31, 0,    O + WO_BSUM,        256  };
    S.s[si++] = { 32, -1, 0,    O + WO_W1,          4096 };
    S.s[si++] = { 33, -1, 0,    O + WO_B1,          64   };
    S.s[si++] = { 34, -1, 0,    O + WO_W2,          576  };
    S.s[si++] = { 35, -1, 0,    O + WO_B2,          9    };
  }

  const int* hl_ptr = (const int*)d_in[3];

  kweights<<<dim3(35), 256, 0, stream>>>(P, S, WF, d_in[7], flag, ghist);
  kfrag<<<dim3(68), 256, 0, stream>>>(WF, FB);
  kprep<<<dim3(NB / 4, 3), 256, 0, stream>>>(d_in[0], d_in[1], hl_ptr, WF, sTx, nar, xpartT, flag, ghist, krank);
  kscatW<<<dim3(16, 3), 256, 0, stream>>>(hl_ptr, nar, ghist, krank, idx, cnt);
  kmainM<<<dim3(513, 3), 256, 0, stream>>>(nar, WF, FB, sTx, xpartT, idx, cnt, zxp);
  kfinalM<<<dim3(NB / 16), 256, 0, stream>>>(WF, FB, xpartT, zxp, hl_ptr, d_out, flag);
}